// Round 13
// baseline (174.775 us; speedup 1.0000x reference)
//
#include <hip/hip_runtime.h>

typedef __attribute__((ext_vector_type(8))) __bf16 bf16x8;
typedef __attribute__((ext_vector_type(4))) float floatx4;
typedef unsigned short u16;
typedef unsigned int u32;

#define KSCALE 0.18033688011112042f  // 0.125 * log2(e)

__device__ __forceinline__ u16 f2bf(float f) {
    union { float f; u32 u; } v; v.f = f;
    u32 r = v.u + 0x7fffu + ((v.u >> 16) & 1u);
    return (u16)(r >> 16);
}

__device__ __forceinline__ u32 pk2bf(float a, float b) {
    union { float f; u32 u; } x, y; x.f = a; y.f = b;
    return __builtin_amdgcn_perm(y.u + 0x8000u, x.u + 0x8000u, 0x07060302);
}

// async global->LDS, 16B/lane; dest = wave-uniform base + lane*16
__device__ __forceinline__ void gl_lds16(const u16* g, u16* l) {
    __builtin_amdgcn_global_load_lds((const __attribute__((address_space(1))) void*)g,
                                     (__attribute__((address_space(3))) void*)l, 16, 0, 0);
}

// ---------------- prep: weight transposes (fp32->bf16) + LayerNorm, one launch ----------------
__global__ __launch_bounds__(256) void prep(const float* __restrict__ Wq, const float* __restrict__ Wkv,
                                            const float* __restrict__ Wo, const float* __restrict__ x,
                                            const float* __restrict__ gamma, const float* __restrict__ beta,
                                            u16* __restrict__ WqkvT, u16* __restrict__ WoT,
                                            u16* __restrict__ xn) {
    __shared__ float tile[64][68];
    __shared__ float ps[4], ps2[4];
    const int bx = blockIdx.x;
    const int t = threadIdx.x;
    if (bx < 768) {
        const int z = bx >> 8, rem = bx & 255;
        const int tr = (rem >> 4) * 64, tc = (rem & 15) * 64;
        const float* in = (z == 0) ? Wq : (z == 1 ? Wkv : Wo);
        u16* out = (z == 0) ? WqkvT : (z == 1 ? WqkvT + (size_t)1024 * 1024 : WoT);
        const int cols = (z == 1) ? 128 : 1024;
        if (tc >= cols) return;
        for (int p = 0; p < 4; p++) {
            int ri = (t >> 4) + p * 16;
            int ci = (t & 15) * 4;
            float4 v = *(const float4*)&in[(size_t)(tr + ri) * cols + tc + ci];
            tile[ri][ci + 0] = v.x; tile[ri][ci + 1] = v.y;
            tile[ri][ci + 2] = v.z; tile[ri][ci + 3] = v.w;
        }
        __syncthreads();
        for (int p = 0; p < 4; p++) {
            int oc = (t >> 4) + p * 16;
            int ir = (t & 15) * 4;
            float s = (z == 1 && (tc + oc) < 64) ? KSCALE : 1.0f;
            ushort4 o;
            o.x = f2bf(tile[ir + 0][oc] * s);
            o.y = f2bf(tile[ir + 1][oc] * s);
            o.z = f2bf(tile[ir + 2][oc] * s);
            o.w = f2bf(tile[ir + 3][oc] * s);
            *(ushort4*)&out[(size_t)(tc + oc) * 1024 + tr + ir] = o;
        }
    } else {
        const int row = bx - 768;
        const float* xr = x + (size_t)row * 1024;
        float4 v = *(const float4*)&xr[t * 4];
        float s = v.x + v.y + v.z + v.w;
        float s2 = v.x * v.x + v.y * v.y + v.z * v.z + v.w * v.w;
        for (int off = 1; off < 64; off <<= 1) {
            s += __shfl_xor(s, off, 64);
            s2 += __shfl_xor(s2, off, 64);
        }
        int w = t >> 6, lane = t & 63;
        if (lane == 0) { ps[w] = s; ps2[w] = s2; }
        __syncthreads();
        float S = ps[0] + ps[1] + ps[2] + ps[3];
        float S2 = ps2[0] + ps2[1] + ps2[2] + ps2[3];
        float mu = S * (1.0f / 1024.0f);
        float var = S2 * (1.0f / 1024.0f) - mu * mu;
        float rstd = rsqrtf(var + 1e-5f);
        ushort4 o;
        o.x = f2bf((v.x - mu) * rstd * gamma[t * 4 + 0] + beta[t * 4 + 0]);
        o.y = f2bf((v.y - mu) * rstd * gamma[t * 4 + 1] + beta[t * 4 + 1]);
        o.z = f2bf((v.z - mu) * rstd * gamma[t * 4 + 2] + beta[t * 4 + 2]);
        o.w = f2bf((v.w - mu) * rstd * gamma[t * 4 + 3] + beta[t * 4 + 3]);
        *(ushort4*)&xn[(size_t)row * 1024 + t * 4] = o;
    }
}

// ---------------- C = A(MxK) @ BT(NxK)^T, 64x128 tiles, BK=64, double-buffered LDS ----------------
template <bool FINAL>
__global__ __launch_bounds__(256) void gemm_bt(const u16* __restrict__ A, const u16* __restrict__ BT,
                                               u16* __restrict__ Cb, float* __restrict__ Cf,
                                               const float* __restrict__ bias, const float* __restrict__ resid,
                                               u16* __restrict__ vt2, int M, int N, int K) {
    __shared__ u16 as_[2 * 64 * 64];    // buf offset 4096
    __shared__ u16 bs_[2 * 128 * 64];   // buf offset 8192
    const int t = threadIdx.x;
    const int w = t >> 6, lane = t & 63, q = lane >> 4, c = lane & 15;
    const int tm = blockIdx.y * 64, tn = blockIdx.x * 128;
    const int wm = (w & 1) * 32, wn = (w >> 1) * 64;

    const int l3 = lane >> 3, sch = lane & 7;
    const int arow = w * 16 + l3;
    const int aswz = (sch ^ (arow & 7)) * 8;
    const int brow = w * 32 + l3;
    const int bswz = (sch ^ (brow & 7)) * 8;
    const u16* ag0 = A + (size_t)(tm + arow) * K + aswz;
    const u16* ag1 = ag0 + (size_t)8 * K;
    const u16* bg0 = BT + (size_t)(tn + brow) * K + bswz;
    const u16* bg1 = bg0 + (size_t)8 * K;
    const u16* bg2 = bg0 + (size_t)16 * K;
    const u16* bg3 = bg0 + (size_t)24 * K;
    u16* al0 = as_ + (w * 16) * 64;
    u16* al1 = as_ + (w * 16 + 8) * 64;
    u16* bl0 = bs_ + (w * 32) * 64;
    u16* bl1 = bs_ + (w * 32 + 8) * 64;
    u16* bl2 = bs_ + (w * 32 + 16) * 64;
    u16* bl3 = bs_ + (w * 32 + 24) * 64;

    const int c7 = c & 7;
    const u16* afp[2][2];
    const u16* bfp[4][2];
#pragma unroll
    for (int i = 0; i < 2; i++)
#pragma unroll
        for (int kk = 0; kk < 2; kk++)
            afp[i][kk] = &as_[(wm + i * 16 + c) * 64 + (((kk * 4 + q) ^ c7) * 8)];
#pragma unroll
    for (int j = 0; j < 4; j++)
#pragma unroll
        for (int kk = 0; kk < 2; kk++)
            bfp[j][kk] = &bs_[(wn + j * 16 + c) * 64 + (((kk * 4 + q) ^ c7) * 8)];

    floatx4 acc[2][4];
    for (int i = 0; i < 2; i++)
        for (int j = 0; j < 4; j++) acc[i][j] = (floatx4){0.f, 0.f, 0.f, 0.f};

    gl_lds16(ag0, al0);
    gl_lds16(ag1, al1);
    gl_lds16(bg0, bl0);
    gl_lds16(bg1, bl1);
    gl_lds16(bg2, bl2);
    gl_lds16(bg3, bl3);
    __syncthreads();

    const int NIT = K >> 6;
#pragma unroll 2
    for (int it = 0; it < NIT; it++) {
        const int cur = it & 1, nxt = cur ^ 1;
        if (it + 1 < NIT) {
            const int k0 = (it + 1) << 6;
            gl_lds16(ag0 + k0, al0 + nxt * 4096);
            gl_lds16(ag1 + k0, al1 + nxt * 4096);
            gl_lds16(bg0 + k0, bl0 + nxt * 8192);
            gl_lds16(bg1 + k0, bl1 + nxt * 8192);
            gl_lds16(bg2 + k0, bl2 + nxt * 8192);
            gl_lds16(bg3 + k0, bl3 + nxt * 8192);
        }
        bf16x8 af[2][2], bf[4][2];
#pragma unroll
        for (int i = 0; i < 2; i++)
#pragma unroll
            for (int kk = 0; kk < 2; kk++)
                af[i][kk] = *(const bf16x8*)(afp[i][kk] + cur * 4096);
#pragma unroll
        for (int j = 0; j < 4; j++)
#pragma unroll
            for (int kk = 0; kk < 2; kk++)
                bf[j][kk] = *(const bf16x8*)(bfp[j][kk] + cur * 8192);
#pragma unroll
        for (int kk = 0; kk < 2; kk++)
#pragma unroll
            for (int i = 0; i < 2; i++)
#pragma unroll
                for (int j = 0; j < 4; j++)
                    acc[i][j] = __builtin_amdgcn_mfma_f32_16x16x32_bf16(af[i][kk], bf[j][kk], acc[i][j], 0, 0, 0);
        __syncthreads();
    }
#pragma unroll
    for (int i = 0; i < 2; i++)
#pragma unroll
        for (int j = 0; j < 4; j++)
#pragma unroll
            for (int r = 0; r < 4; r++) {
                int row = tm + wm + i * 16 + q * 4 + r;
                int col = tn + wn + j * 16 + c;
                float v = acc[i][j][r];
                if (FINAL) {
                    Cf[(size_t)row * N + col] = v + bias[col] + resid[(size_t)row * N + col];
                } else if (col < 1088) {
                    Cb[(size_t)row * N + col] = f2bf(v);
                } else {
                    // V: vt2[b][d][s'] with per-32 s-interleave u' = ((u>>2)&3)*8 + (u>>4)*4 + (u&3)
                    int d = col - 1088;
                    int bb = row >> 11, sl = row & 2047;
                    int Bk = sl >> 5, u = sl & 31;
                    int up = ((u >> 2) & 3) * 8 + ((u >> 4) << 2) + (u & 3);
                    vt2[((size_t)(bb * 64 + d)) * 2048 + Bk * 32 + up] = f2bf(v);
                }
            }
}

// ---------------- split-s flash attention, MQA: 32q/wave, each block does HALF the s-range ----------------
// no-max exp2 softmax => partial (O, L) over disjoint s-ranges are directly additive.
// Writes unnormalized fp32 O-partials + L-partials; combine kernel finishes.
union Vf { bf16x8 v; u32 w[4]; };

__global__ __launch_bounds__(256, 4) void attn11(const u16* __restrict__ qkv, const u16* __restrict__ vt2,
                                                 float* __restrict__ Opart, float* __restrict__ Lpart) {
    __shared__ u16 ksm[2][64 * 64];   // [s][d]
    __shared__ u16 vsm[2][64 * 64];   // [d][s']
    const int t = threadIdx.x;
    const int w = t >> 6, lane = t & 63;
    const int q = lane >> 4, c = lane & 15;
    const int qt = blockIdx.x, hg = blockIdx.y;
    const int zz = blockIdx.z, b = zz >> 1, sh = zz & 1;
    const int h = hg * 4 + w;
    const size_t qrow0 = (size_t)b * 2048 + qt * 32;
    const u16* kbase = qkv + (size_t)b * 2048 * 1152 + 1024 + (size_t)(sh * 1024) * 1152;
    const u16* vbase = vt2 + (size_t)b * 64 * 2048 + sh * 1024;

    const int l3 = lane >> 3, sch = lane & 7;
    const int srow = w * 16 + l3;
    const int swz = (sch ^ (srow & 7)) * 8;
    const u16* kg0 = kbase + (size_t)srow * 1152 + swz;
    const u16* kg1 = kg0 + (size_t)8 * 1152;
    const u16* vg0 = vbase + (size_t)srow * 2048 + swz;
    const u16* vg1 = vg0 + (size_t)8 * 2048;
    u16* kl0 = &ksm[0][(w * 16) * 64];
    u16* kl1 = &ksm[0][(w * 16 + 8) * 64];
    u16* vl0 = &vsm[0][(w * 16) * 64];
    u16* vl1 = &vsm[0][(w * 16 + 8) * 64];

    const int c7 = c & 7;
    const u16* kfp[4][2];
    const u16* vfp[4][2];
#pragma unroll
    for (int ni = 0; ni < 4; ni++)
#pragma unroll
        for (int kk = 0; kk < 2; kk++) {
            kfp[ni][kk] = &ksm[0][(ni * 16 + c) * 64 + (((kk * 4 + q) ^ c7) * 8)];
            vfp[ni][kk] = &vsm[0][(ni * 16 + c) * 64 + (((kk * 4 + q) ^ c7) * 8)];
        }

    bf16x8 qf[2][2];
#pragma unroll
    for (int mi = 0; mi < 2; mi++)
#pragma unroll
        for (int kk = 0; kk < 2; kk++)
            qf[mi][kk] = *(const bf16x8*)&qkv[(qrow0 + mi * 16 + c) * 1152 + h * 64 + kk * 32 + q * 8];

    floatx4 O[4][2], Lacc[2];
#pragma unroll
    for (int di = 0; di < 4; di++)
#pragma unroll
        for (int mi = 0; mi < 2; mi++) O[di][mi] = (floatx4){0.f, 0.f, 0.f, 0.f};
    Lacc[0] = (floatx4){0.f, 0.f, 0.f, 0.f};
    Lacc[1] = (floatx4){0.f, 0.f, 0.f, 0.f};
    Vf ones;
    ones.w[0] = ones.w[1] = ones.w[2] = ones.w[3] = 0x3F803F80u;

    gl_lds16(kg0, kl0);
    gl_lds16(kg1, kl1);
    gl_lds16(vg0, vl0);
    gl_lds16(vg1, vl1);
    kg0 += (size_t)64 * 1152; kg1 += (size_t)64 * 1152; vg0 += 64; vg1 += 64;
    __syncthreads();

#pragma unroll 2
    for (int tt = 0; tt < 16; tt++) {
        const int cur = tt & 1, nxt = cur ^ 1;
        if (tt < 15) {
            gl_lds16(kg0, kl0 + nxt * 4096);
            gl_lds16(kg1, kl1 + nxt * 4096);
            gl_lds16(vg0, vl0 + nxt * 4096);
            gl_lds16(vg1, vl1 + nxt * 4096);
            kg0 += (size_t)64 * 1152; kg1 += (size_t)64 * 1152; vg0 += 64; vg1 += 64;
        }

        bf16x8 kf[4][2];
        Vf vf[4][2];
#pragma unroll
        for (int ni = 0; ni < 4; ni++)
#pragma unroll
            for (int kk = 0; kk < 2; kk++)
                kf[ni][kk] = *(const bf16x8*)(kfp[ni][kk] + cur * 4096);
#pragma unroll
        for (int di = 0; di < 4; di++)
#pragma unroll
            for (int kk = 0; kk < 2; kk++)
                vf[di][kk].v = *(const bf16x8*)(vfp[di][kk] + cur * 4096);

        // ---- QK^T (S^T; scale folded into K) ----
        floatx4 sacc[4][2];
#pragma unroll
        for (int ni = 0; ni < 4; ni++)
#pragma unroll
            for (int mi = 0; mi < 2; mi++) {
                floatx4 z = (floatx4){0.f, 0.f, 0.f, 0.f};
                z = __builtin_amdgcn_mfma_f32_16x16x32_bf16(kf[ni][0], qf[mi][0], z, 0, 0, 0);
                z = __builtin_amdgcn_mfma_f32_16x16x32_bf16(kf[ni][1], qf[mi][1], z, 0, 0, 0);
                sacc[ni][mi] = z;
            }

        // ---- p = exp2(s) raw v_exp, pack ----
        u32 pk[4][2][2];
#pragma unroll
        for (int mi = 0; mi < 2; mi++)
#pragma unroll
            for (int ni = 0; ni < 4; ni++) {
                float p0 = __builtin_amdgcn_exp2f(sacc[ni][mi][0]);
                float p1 = __builtin_amdgcn_exp2f(sacc[ni][mi][1]);
                float p2 = __builtin_amdgcn_exp2f(sacc[ni][mi][2]);
                float p3 = __builtin_amdgcn_exp2f(sacc[ni][mi][3]);
                pk[ni][mi][0] = pk2bf(p0, p1);
                pk[ni][mi][1] = pk2bf(p2, p3);
            }

        // ---- PV + L ----
#pragma unroll
        for (int kk = 0; kk < 2; kk++) {
            Vf pf[2];
#pragma unroll
            for (int mi = 0; mi < 2; mi++) {
                pf[mi].w[0] = pk[2 * kk][mi][0];
                pf[mi].w[1] = pk[2 * kk][mi][1];
                pf[mi].w[2] = pk[2 * kk + 1][mi][0];
                pf[mi].w[3] = pk[2 * kk + 1][mi][1];
            }
#pragma unroll
            for (int di = 0; di < 4; di++)
#pragma unroll
                for (int mi = 0; mi < 2; mi++)
                    O[di][mi] = __builtin_amdgcn_mfma_f32_16x16x32_bf16(vf[di][kk].v, pf[mi].v, O[di][mi], 0, 0, 0);
#pragma unroll
            for (int mi = 0; mi < 2; mi++)
                Lacc[mi] = __builtin_amdgcn_mfma_f32_16x16x32_bf16(ones.v, pf[mi].v, Lacc[mi], 0, 0, 0);
        }

        __syncthreads();
    }

    // ---- write unnormalized partials ----
    float* Op = Opart + (size_t)sh * 4096 * 1024;
#pragma unroll
    for (int di = 0; di < 4; di++)
#pragma unroll
        for (int mi = 0; mi < 2; mi++)
            *(floatx4*)&Op[(qrow0 + mi * 16 + c) * 1024 + h * 64 + di * 16 + q * 4] = O[di][mi];
    if (q == 0) {
#pragma unroll
        for (int mi = 0; mi < 2; mi++)
            Lpart[((size_t)sh * 4096 + qrow0 + mi * 16 + c) * 16 + h] = Lacc[mi][0];
    }
}

// ---------------- combine: attnO = bf16((O0+O1)/(L0+L1)) ----------------
__global__ __launch_bounds__(256) void combine(const float* __restrict__ Opart, const float* __restrict__ Lpart,
                                               u16* __restrict__ attnO) {
    const int row = blockIdx.x, t = threadIdx.x;
    const int col = t * 4;
    float4 o0 = *(const float4*)&Opart[(size_t)row * 1024 + col];
    float4 o1 = *(const float4*)&Opart[(size_t)(4096 + row) * 1024 + col];
    const int hh = col >> 6;
    float L = Lpart[(size_t)row * 16 + hh] + Lpart[(size_t)(4096 + row) * 16 + hh];
    float inv = 1.0f / L;
    ushort4 o;
    o.x = f2bf((o0.x + o1.x) * inv);
    o.y = f2bf((o0.y + o1.y) * inv);
    o.z = f2bf((o0.z + o1.z) * inv);
    o.w = f2bf((o0.w + o1.w) * inv);
    *(ushort4*)&attnO[(size_t)row * 1024 + col] = o;
}

extern "C" void kernel_launch(void* const* d_in, const int* in_sizes, int n_in,
                              void* d_out, int out_size, void* d_ws, size_t ws_size,
                              hipStream_t stream) {
    const float* x = (const float*)d_in[0];
    const float* gamma = (const float*)d_in[1];
    const float* beta = (const float*)d_in[2];
    const float* Wq = (const float*)d_in[3];
    const float* Wkv = (const float*)d_in[4];
    const float* Wo = (const float*)d_in[5];
    const float* bo = (const float*)d_in[6];
    float* out = (float*)d_out;

    u16* WqkvT = (u16*)d_ws;                         // 1152*1024
    u16* WoT = WqkvT + (size_t)1152 * 1024;          // 1024*1024
    u16* xn = WoT + (size_t)1024 * 1024;             // 4096*1024
    u16* qkv = xn + (size_t)4096 * 1024;             // 4096*1152
    u16* vt2 = qkv + (size_t)4096 * 1152;            // 2*64*2048
    float* Opart = (float*)(vt2 + (size_t)2 * 64 * 2048);   // 2*4096*1024 fp32
    float* Lpart = Opart + (size_t)2 * 4096 * 1024;          // 2*4096*16 fp32
    u16* attnO = xn;                                 // alias: xn dead after QKV GEMM

    prep<<<4864, 256, 0, stream>>>(Wq, Wkv, Wo, x, gamma, beta, WqkvT, WoT, xn);
    gemm_bt<false><<<dim3(9, 64), 256, 0, stream>>>(xn, WqkvT, qkv, nullptr, nullptr, nullptr, vt2,
                                                    4096, 1152, 1024);
    attn11<<<dim3(64, 4, 4), 256, 0, stream>>>(qkv, vt2, Opart, Lpart);
    combine<<<4096, 256, 0, stream>>>(Opart, Lpart, attnO);
    gemm_bt<true><<<dim3(8, 64), 256, 0, stream>>>(attnO, WoT, nullptr, out, bo, x, nullptr,
                                                   4096, 1024, 1024);
}

// Round 14
// 164.327 us; speedup vs baseline: 1.0636x; 1.0636x over previous
//
#include <hip/hip_runtime.h>

typedef __attribute__((ext_vector_type(8))) __bf16 bf16x8;
typedef __attribute__((ext_vector_type(4))) float floatx4;
typedef unsigned short u16;
typedef unsigned int u32;

#define KSCALE 0.18033688011112042f  // 0.125 * log2(e)

__device__ __forceinline__ u16 f2bf(float f) {
    union { float f; u32 u; } v; v.f = f;
    u32 r = v.u + 0x7fffu + ((v.u >> 16) & 1u);
    return (u16)(r >> 16);
}

__device__ __forceinline__ u32 pk2bf(float a, float b) {
    union { float f; u32 u; } x, y; x.f = a; y.f = b;
    return __builtin_amdgcn_perm(y.u + 0x8000u, x.u + 0x8000u, 0x07060302);
}

// async global->LDS, 16B/lane; dest = wave-uniform base + lane*16
__device__ __forceinline__ void gl_lds16(const u16* g, u16* l) {
    __builtin_amdgcn_global_load_lds((const __attribute__((address_space(1))) void*)g,
                                     (__attribute__((address_space(3))) void*)l, 16, 0, 0);
}

// ---------------- prep: weight transposes (fp32->bf16) + LayerNorm, one launch ----------------
__global__ __launch_bounds__(256) void prep(const float* __restrict__ Wq, const float* __restrict__ Wkv,
                                            const float* __restrict__ Wo, const float* __restrict__ x,
                                            const float* __restrict__ gamma, const float* __restrict__ beta,
                                            u16* __restrict__ WqkvT, u16* __restrict__ WoT,
                                            u16* __restrict__ xn) {
    __shared__ float tile[64][68];
    __shared__ float ps[4], ps2[4];
    const int bx = blockIdx.x;
    const int t = threadIdx.x;
    if (bx < 768) {
        const int z = bx >> 8, rem = bx & 255;
        const int tr = (rem >> 4) * 64, tc = (rem & 15) * 64;
        const float* in = (z == 0) ? Wq : (z == 1 ? Wkv : Wo);
        u16* out = (z == 0) ? WqkvT : (z == 1 ? WqkvT + (size_t)1024 * 1024 : WoT);
        const int cols = (z == 1) ? 128 : 1024;
        if (tc >= cols) return;
        for (int p = 0; p < 4; p++) {
            int ri = (t >> 4) + p * 16;
            int ci = (t & 15) * 4;
            float4 v = *(const float4*)&in[(size_t)(tr + ri) * cols + tc + ci];
            tile[ri][ci + 0] = v.x; tile[ri][ci + 1] = v.y;
            tile[ri][ci + 2] = v.z; tile[ri][ci + 3] = v.w;
        }
        __syncthreads();
        for (int p = 0; p < 4; p++) {
            int oc = (t >> 4) + p * 16;
            int ir = (t & 15) * 4;
            float s = (z == 1 && (tc + oc) < 64) ? KSCALE : 1.0f;
            ushort4 o;
            o.x = f2bf(tile[ir + 0][oc] * s);
            o.y = f2bf(tile[ir + 1][oc] * s);
            o.z = f2bf(tile[ir + 2][oc] * s);
            o.w = f2bf(tile[ir + 3][oc] * s);
            *(ushort4*)&out[(size_t)(tc + oc) * 1024 + tr + ir] = o;
        }
    } else {
        const int row = bx - 768;
        const float* xr = x + (size_t)row * 1024;
        float4 v = *(const float4*)&xr[t * 4];
        float s = v.x + v.y + v.z + v.w;
        float s2 = v.x * v.x + v.y * v.y + v.z * v.z + v.w * v.w;
        for (int off = 1; off < 64; off <<= 1) {
            s += __shfl_xor(s, off, 64);
            s2 += __shfl_xor(s2, off, 64);
        }
        int w = t >> 6, lane = t & 63;
        if (lane == 0) { ps[w] = s; ps2[w] = s2; }
        __syncthreads();
        float S = ps[0] + ps[1] + ps[2] + ps[3];
        float S2 = ps2[0] + ps2[1] + ps2[2] + ps2[3];
        float mu = S * (1.0f / 1024.0f);
        float var = S2 * (1.0f / 1024.0f) - mu * mu;
        float rstd = rsqrtf(var + 1e-5f);
        ushort4 o;
        o.x = f2bf((v.x - mu) * rstd * gamma[t * 4 + 0] + beta[t * 4 + 0]);
        o.y = f2bf((v.y - mu) * rstd * gamma[t * 4 + 1] + beta[t * 4 + 1]);
        o.z = f2bf((v.z - mu) * rstd * gamma[t * 4 + 2] + beta[t * 4 + 2]);
        o.w = f2bf((v.w - mu) * rstd * gamma[t * 4 + 3] + beta[t * 4 + 3]);
        *(ushort4*)&xn[(size_t)row * 1024 + t * 4] = o;
    }
}

// ---------------- C = A(MxK) @ BT(NxK)^T, 64x128 tiles, BK=64, double-buffered LDS ----------------
template <bool FINAL>
__global__ __launch_bounds__(256) void gemm_bt(const u16* __restrict__ A, const u16* __restrict__ BT,
                                               u16* __restrict__ Cb, float* __restrict__ Cf,
                                               const float* __restrict__ bias, const float* __restrict__ resid,
                                               u16* __restrict__ vt2, int M, int N, int K) {
    __shared__ u16 as_[2 * 64 * 64];    // buf offset 4096
    __shared__ u16 bs_[2 * 128 * 64];   // buf offset 8192
    const int t = threadIdx.x;
    const int w = t >> 6, lane = t & 63, q = lane >> 4, c = lane & 15;
    const int tm = blockIdx.y * 64, tn = blockIdx.x * 128;
    const int wm = (w & 1) * 32, wn = (w >> 1) * 64;

    const int l3 = lane >> 3, sch = lane & 7;
    const int arow = w * 16 + l3;
    const int aswz = (sch ^ (arow & 7)) * 8;
    const int brow = w * 32 + l3;
    const int bswz = (sch ^ (brow & 7)) * 8;
    const u16* ag0 = A + (size_t)(tm + arow) * K + aswz;
    const u16* ag1 = ag0 + (size_t)8 * K;
    const u16* bg0 = BT + (size_t)(tn + brow) * K + bswz;
    const u16* bg1 = bg0 + (size_t)8 * K;
    const u16* bg2 = bg0 + (size_t)16 * K;
    const u16* bg3 = bg0 + (size_t)24 * K;
    u16* al0 = as_ + (w * 16) * 64;
    u16* al1 = as_ + (w * 16 + 8) * 64;
    u16* bl0 = bs_ + (w * 32) * 64;
    u16* bl1 = bs_ + (w * 32 + 8) * 64;
    u16* bl2 = bs_ + (w * 32 + 16) * 64;
    u16* bl3 = bs_ + (w * 32 + 24) * 64;

    const int c7 = c & 7;
    const u16* afp[2][2];
    const u16* bfp[4][2];
#pragma unroll
    for (int i = 0; i < 2; i++)
#pragma unroll
        for (int kk = 0; kk < 2; kk++)
            afp[i][kk] = &as_[(wm + i * 16 + c) * 64 + (((kk * 4 + q) ^ c7) * 8)];
#pragma unroll
    for (int j = 0; j < 4; j++)
#pragma unroll
        for (int kk = 0; kk < 2; kk++)
            bfp[j][kk] = &bs_[(wn + j * 16 + c) * 64 + (((kk * 4 + q) ^ c7) * 8)];

    floatx4 acc[2][4];
    for (int i = 0; i < 2; i++)
        for (int j = 0; j < 4; j++) acc[i][j] = (floatx4){0.f, 0.f, 0.f, 0.f};

    gl_lds16(ag0, al0);
    gl_lds16(ag1, al1);
    gl_lds16(bg0, bl0);
    gl_lds16(bg1, bl1);
    gl_lds16(bg2, bl2);
    gl_lds16(bg3, bl3);
    __syncthreads();

    const int NIT = K >> 6;
#pragma unroll 2
    for (int it = 0; it < NIT; it++) {
        const int cur = it & 1, nxt = cur ^ 1;
        if (it + 1 < NIT) {
            const int k0 = (it + 1) << 6;
            gl_lds16(ag0 + k0, al0 + nxt * 4096);
            gl_lds16(ag1 + k0, al1 + nxt * 4096);
            gl_lds16(bg0 + k0, bl0 + nxt * 8192);
            gl_lds16(bg1 + k0, bl1 + nxt * 8192);
            gl_lds16(bg2 + k0, bl2 + nxt * 8192);
            gl_lds16(bg3 + k0, bl3 + nxt * 8192);
        }
        bf16x8 af[2][2], bf[4][2];
#pragma unroll
        for (int i = 0; i < 2; i++)
#pragma unroll
            for (int kk = 0; kk < 2; kk++)
                af[i][kk] = *(const bf16x8*)(afp[i][kk] + cur * 4096);
#pragma unroll
        for (int j = 0; j < 4; j++)
#pragma unroll
            for (int kk = 0; kk < 2; kk++)
                bf[j][kk] = *(const bf16x8*)(bfp[j][kk] + cur * 8192);
#pragma unroll
        for (int kk = 0; kk < 2; kk++)
#pragma unroll
            for (int i = 0; i < 2; i++)
#pragma unroll
                for (int j = 0; j < 4; j++)
                    acc[i][j] = __builtin_amdgcn_mfma_f32_16x16x32_bf16(af[i][kk], bf[j][kk], acc[i][j], 0, 0, 0);
        __syncthreads();
    }
#pragma unroll
    for (int i = 0; i < 2; i++)
#pragma unroll
        for (int j = 0; j < 4; j++)
#pragma unroll
            for (int r = 0; r < 4; r++) {
                int row = tm + wm + i * 16 + q * 4 + r;
                int col = tn + wn + j * 16 + c;
                float v = acc[i][j][r];
                if (FINAL) {
                    Cf[(size_t)row * N + col] = v + bias[col] + resid[(size_t)row * N + col];
                } else if (col < 1088) {
                    Cb[(size_t)row * N + col] = f2bf(v);
                } else {
                    // V: vt2[b][d][s'] with per-32 s-interleave u' = ((u>>2)&3)*8 + (u>>4)*4 + (u&3)
                    int d = col - 1088;
                    int bb = row >> 11, sl = row & 2047;
                    int Bk = sl >> 5, u = sl & 31;
                    int up = ((u >> 2) & 3) * 8 + ((u >> 4) << 2) + (u & 3);
                    vt2[((size_t)(bb * 64 + d)) * 2048 + Bk * 32 + up] = f2bf(v);
                }
            }
}

// ---------------- flash attention, MQA: 4 waves = 4 heads, 32 q-rows/wave (best known) ----------------
// No-max exp2 softmax (scale folded into K), L via ones-MFMA, raw v_exp, hoisted frag pointers.
union Vf { bf16x8 v; u32 w[4]; };

__global__ __launch_bounds__(256, 2) void attn9(const u16* __restrict__ qkv, const u16* __restrict__ vt2,
                                                u16* __restrict__ out) {
    __shared__ u16 ksm[2][64 * 64];   // [s][d]
    __shared__ u16 vsm[2][64 * 64];   // [d][s']
    const int t = threadIdx.x;
    const int w = t >> 6, lane = t & 63;
    const int q = lane >> 4, c = lane & 15;
    const int qt = blockIdx.x, hg = blockIdx.y, b = blockIdx.z;
    const int h = hg * 4 + w;
    const size_t qrow0 = (size_t)b * 2048 + qt * 32;
    const u16* kbase = qkv + (size_t)b * 2048 * 1152 + 1024;
    const u16* vbase = vt2 + (size_t)b * 64 * 2048;

    const int l3 = lane >> 3, sch = lane & 7;
    const int srow = w * 16 + l3;
    const int swz = (sch ^ (srow & 7)) * 8;
    const u16* kg0 = kbase + (size_t)srow * 1152 + swz;
    const u16* kg1 = kg0 + (size_t)8 * 1152;
    const u16* vg0 = vbase + (size_t)srow * 2048 + swz;
    const u16* vg1 = vg0 + (size_t)8 * 2048;
    u16* kl0 = &ksm[0][(w * 16) * 64];
    u16* kl1 = &ksm[0][(w * 16 + 8) * 64];
    u16* vl0 = &vsm[0][(w * 16) * 64];
    u16* vl1 = &vsm[0][(w * 16 + 8) * 64];

    const int c7 = c & 7;
    const u16* kfp[4][2];
    const u16* vfp[4][2];
#pragma unroll
    for (int ni = 0; ni < 4; ni++)
#pragma unroll
        for (int kk = 0; kk < 2; kk++) {
            kfp[ni][kk] = &ksm[0][(ni * 16 + c) * 64 + (((kk * 4 + q) ^ c7) * 8)];
            vfp[ni][kk] = &vsm[0][(ni * 16 + c) * 64 + (((kk * 4 + q) ^ c7) * 8)];
        }

    bf16x8 qf[2][2];
#pragma unroll
    for (int mi = 0; mi < 2; mi++)
#pragma unroll
        for (int kk = 0; kk < 2; kk++)
            qf[mi][kk] = *(const bf16x8*)&qkv[(qrow0 + mi * 16 + c) * 1152 + h * 64 + kk * 32 + q * 8];

    floatx4 O[4][2], Lacc[2];
#pragma unroll
    for (int di = 0; di < 4; di++)
#pragma unroll
        for (int mi = 0; mi < 2; mi++) O[di][mi] = (floatx4){0.f, 0.f, 0.f, 0.f};
    Lacc[0] = (floatx4){0.f, 0.f, 0.f, 0.f};
    Lacc[1] = (floatx4){0.f, 0.f, 0.f, 0.f};
    Vf ones;
    ones.w[0] = ones.w[1] = ones.w[2] = ones.w[3] = 0x3F803F80u;

    gl_lds16(kg0, kl0);
    gl_lds16(kg1, kl1);
    gl_lds16(vg0, vl0);
    gl_lds16(vg1, vl1);
    kg0 += (size_t)64 * 1152; kg1 += (size_t)64 * 1152; vg0 += 64; vg1 += 64;
    __syncthreads();

#pragma unroll 2
    for (int tt = 0; tt < 32; tt++) {
        const int cur = tt & 1, nxt = cur ^ 1;
        if (tt < 31) {
            gl_lds16(kg0, kl0 + nxt * 4096);
            gl_lds16(kg1, kl1 + nxt * 4096);
            gl_lds16(vg0, vl0 + nxt * 4096);
            gl_lds16(vg1, vl1 + nxt * 4096);
            kg0 += (size_t)64 * 1152; kg1 += (size_t)64 * 1152; vg0 += 64; vg1 += 64;
        }

        bf16x8 kf[4][2];
        Vf vf[4][2];
#pragma unroll
        for (int ni = 0; ni < 4; ni++)
#pragma unroll
            for (int kk = 0; kk < 2; kk++)
                kf[ni][kk] = *(const bf16x8*)(kfp[ni][kk] + cur * 4096);
#pragma unroll
        for (int di = 0; di < 4; di++)
#pragma unroll
            for (int kk = 0; kk < 2; kk++)
                vf[di][kk].v = *(const bf16x8*)(vfp[di][kk] + cur * 4096);

        // ---- QK^T (S^T; scale folded into K) ----
        floatx4 sacc[4][2];
#pragma unroll
        for (int ni = 0; ni < 4; ni++)
#pragma unroll
            for (int mi = 0; mi < 2; mi++) {
                floatx4 z = (floatx4){0.f, 0.f, 0.f, 0.f};
                z = __builtin_amdgcn_mfma_f32_16x16x32_bf16(kf[ni][0], qf[mi][0], z, 0, 0, 0);
                z = __builtin_amdgcn_mfma_f32_16x16x32_bf16(kf[ni][1], qf[mi][1], z, 0, 0, 0);
                sacc[ni][mi] = z;
            }

        // ---- p = exp2(s) raw v_exp, pack ----
        u32 pk[4][2][2];
#pragma unroll
        for (int mi = 0; mi < 2; mi++)
#pragma unroll
            for (int ni = 0; ni < 4; ni++) {
                float p0 = __builtin_amdgcn_exp2f(sacc[ni][mi][0]);
                float p1 = __builtin_amdgcn_exp2f(sacc[ni][mi][1]);
                float p2 = __builtin_amdgcn_exp2f(sacc[ni][mi][2]);
                float p3 = __builtin_amdgcn_exp2f(sacc[ni][mi][3]);
                pk[ni][mi][0] = pk2bf(p0, p1);
                pk[ni][mi][1] = pk2bf(p2, p3);
            }

        // ---- PV + L ----
#pragma unroll
        for (int kk = 0; kk < 2; kk++) {
            Vf pf[2];
#pragma unroll
            for (int mi = 0; mi < 2; mi++) {
                pf[mi].w[0] = pk[2 * kk][mi][0];
                pf[mi].w[1] = pk[2 * kk][mi][1];
                pf[mi].w[2] = pk[2 * kk + 1][mi][0];
                pf[mi].w[3] = pk[2 * kk + 1][mi][1];
            }
#pragma unroll
            for (int di = 0; di < 4; di++)
#pragma unroll
                for (int mi = 0; mi < 2; mi++)
                    O[di][mi] = __builtin_amdgcn_mfma_f32_16x16x32_bf16(vf[di][kk].v, pf[mi].v, O[di][mi], 0, 0, 0);
#pragma unroll
            for (int mi = 0; mi < 2; mi++)
                Lacc[mi] = __builtin_amdgcn_mfma_f32_16x16x32_bf16(ones.v, pf[mi].v, Lacc[mi], 0, 0, 0);
        }

        __syncthreads();
    }

    float inv[2] = {1.0f / Lacc[0][0], 1.0f / Lacc[1][0]};
#pragma unroll
    for (int di = 0; di < 4; di++)
#pragma unroll
        for (int mi = 0; mi < 2; mi++) {
            ushort4 o;
            o.x = f2bf(O[di][mi][0] * inv[mi]);
            o.y = f2bf(O[di][mi][1] * inv[mi]);
            o.z = f2bf(O[di][mi][2] * inv[mi]);
            o.w = f2bf(O[di][mi][3] * inv[mi]);
            *(ushort4*)&out[(qrow0 + mi * 16 + c) * 1024 + h * 64 + di * 16 + q * 4] = o;
        }
}

extern "C" void kernel_launch(void* const* d_in, const int* in_sizes, int n_in,
                              void* d_out, int out_size, void* d_ws, size_t ws_size,
                              hipStream_t stream) {
    const float* x = (const float*)d_in[0];
    const float* gamma = (const float*)d_in[1];
    const float* beta = (const float*)d_in[2];
    const float* Wq = (const float*)d_in[3];
    const float* Wkv = (const float*)d_in[4];
    const float* Wo = (const float*)d_in[5];
    const float* bo = (const float*)d_in[6];
    float* out = (float*)d_out;

    u16* WqkvT = (u16*)d_ws;                         // 1152*1024
    u16* WoT = WqkvT + (size_t)1152 * 1024;          // 1024*1024
    u16* xn = WoT + (size_t)1024 * 1024;             // 4096*1024
    u16* qkv = xn + (size_t)4096 * 1024;             // 4096*1152
    u16* vt2 = qkv + (size_t)4096 * 1152;            // 2*64*2048
    u16* attnO = xn;                                 // alias: xn dead after QKV GEMM

    prep<<<4864, 256, 0, stream>>>(Wq, Wkv, Wo, x, gamma, beta, WqkvT, WoT, xn);
    gemm_bt<false><<<dim3(9, 64), 256, 0, stream>>>(xn, WqkvT, qkv, nullptr, nullptr, nullptr, vt2,
                                                    4096, 1152, 1024);
    attn9<<<dim3(64, 4, 2), 256, 0, stream>>>(qkv, vt2, attnO);
    gemm_bt<true><<<dim3(8, 64), 256, 0, stream>>>(attnO, WoT, nullptr, out, bo, x, nullptr,
                                                   4096, 1024, 1024);
}